// Round 13
// baseline (125.294 us; speedup 1.0000x reference)
//
#include <hip/hip_runtime.h>
#include <hip/hip_bf16.h>
#include <math.h>

#define BS 4096
#define DIM 2048
#define EPSV 1e-6f

typedef unsigned short u16;
typedef float f32x4 __attribute__((ext_vector_type(4)));
typedef __bf16 bf16x8 __attribute__((ext_vector_type(8)));

__device__ inline u16 f2bf(float f) {
  unsigned u = __float_as_uint(f);
  unsigned r = (u + 0x7fffu + ((u >> 16) & 1u)) >> 16;
  return (u16)r;
}

__device__ inline void gload16(const u16* g, u16* l) {
  __builtin_amdgcn_global_load_lds((const __attribute__((address_space(1))) unsigned int*)g,
                                   (__attribute__((address_space(3))) unsigned int*)l,
                                   16, 0, 0);
}

// ---------------- prep: f32 -> bf16 copies + per-row sum / sumsq ----------------
__global__ __launch_bounds__(256) void prep_kernel(
    const float* __restrict__ h1, const float* __restrict__ h2,
    u16* __restrict__ A, u16* __restrict__ B,
    float* __restrict__ sq1, float* __restrict__ s1,
    float* __restrict__ sq2, float* __restrict__ s2) {
  int b = blockIdx.x;
  const float* src; u16* dst; float* sqo; float* so; int row;
  if (b < BS) { src = h1; dst = A; sqo = sq1; so = s1; row = b; }
  else        { src = h2; dst = B; sqo = sq2; so = s2; row = b - BS; }
  src += (size_t)row * DIM;
  dst += (size_t)row * DIM;
  int t = threadIdx.x;
  float sq = 0.f, s = 0.f;
#pragma unroll
  for (int it = 0; it < DIM / (256 * 4); ++it) {
    int idx = (it * 256 + t) * 4;
    float4 v = *(const float4*)(src + idx);
    sq += v.x * v.x + v.y * v.y + v.z * v.z + v.w * v.w;
    s  += v.x + v.y + v.z + v.w;
    ushort4 o;
    o.x = f2bf(v.x); o.y = f2bf(v.y); o.z = f2bf(v.z); o.w = f2bf(v.w);
    *(ushort4*)(dst + idx) = o;
  }
#pragma unroll
  for (int m = 32; m; m >>= 1) { sq += __shfl_xor(sq, m, 64); s += __shfl_xor(s, m, 64); }
  __shared__ float lsq[4], ls[4];
  if ((t & 63) == 0) { lsq[t >> 6] = sq; ls[t >> 6] = s; }
  __syncthreads();
  if (t == 0) {
    sqo[row] = lsq[0] + lsq[1] + lsq[2] + lsq[3];
    so[row]  = ls[0] + ls[1] + ls[2] + ls[3];
  }
}

// ---------------- GEMM: 256x256, BK=64, 2-slot LDS, 4-phase m201-style schedule ----------------
// 512 thr = 8 waves (2M x 4N), wave tile 128x64, acc[8][4]=128 regs, 1 block/CU.
// LDS [2 slots][A_k0,A_k1,B_k0,B_k1][16KB] = 128 KB. Sub-arrays are 256x32 with the
// R10-verified 0-conflict swizzle (chunk ^= (row>>1)&3, both sides).
// Phase p of tile T: {subtile ds_reads; stage 1 half of T+1 (2 gloads); [even p:
// vmcnt(4) certifying the 2 halves needed 2 phases later]; s_barrier; lgkmcnt(0);
// sched_barrier; setprio(1); 16 MFMA; setprio(0); s_barrier}. In-flight never <4.
// Ledger (FIFO): stage order per tile = A_k0,B_k0,A_k1,B_k1 at phases 1..4;
// prologue stages tile0 + vmcnt(4) => enters loop with [A_k1,B_k1] outstanding.
#define BKT 64
#define NT64 (DIM / BKT)

__global__ __launch_bounds__(512, 2) void gemm_select_kernel(
    const u16* __restrict__ A, const u16* __restrict__ B,
    const float* __restrict__ sq1, const float* __restrict__ s1,
    const float* __restrict__ sq2, const float* __restrict__ s2,
    const int* __restrict__ lab1, const int* __restrict__ lab2,
    float4* __restrict__ part) {
  __shared__ __align__(16) u16 lds[2][4][8192];
  int tid = threadIdx.x;
  int w = tid >> 6, l = tid & 63;
  int wr = w >> 2, wc = w & 3;
  int g = l >> 4, c = l & 15;
  int by = blockIdx.x >> 4, bx = blockIdx.x & 15;
  const int rowB = by * 256, colB = bx * 256;

  // staging geometry (R10-verified): per 16KB sub-array, unit u = q*512+tid,
  // row = u>>2, ch_log = (u&3)^((u>>3)&3); q=1 adds 128 rows.
  int srow = tid >> 2;
  int schunk = (tid & 3) ^ ((tid >> 3) & 3);
  const u16* gA = A + (size_t)(rowB + srow) * DIM + schunk * 8;
  const u16* gB = B + (size_t)(colB + srow) * DIM + schunk * 8;
  const size_t rstep = (size_t)128 * DIM;

#define STAGE_SUB(T, S) do {                                                    \
    const u16* gp_ = ((S) < 2 ? gA : gB) + (size_t)(T) * BKT + ((S) & 1) * 32;  \
    u16* dp_ = &lds[(T) & 1][S][tid * 8];                                       \
    gload16(gp_, dp_);                                                          \
    gload16(gp_ + rstep, dp_ + 4096); } while (0)

  const int xc = (g ^ ((c >> 1) & 3)) * 8;

#define READ_A(AF, SL, KK) do {                                                 \
    _Pragma("unroll") for (int mi_ = 0; mi_ < 8; ++mi_)                         \
      AF[mi_] = *(const bf16x8*)&lds[SL][KK][(wr * 128 + mi_ * 16 + c) * 32 + xc]; } while (0)
#define READ_B2(BF, SL, KK, NB) do {                                            \
    _Pragma("unroll") for (int nj_ = 0; nj_ < 2; ++nj_)                         \
      BF[nj_] = *(const bf16x8*)&lds[SL][2 + (KK)][(wc * 64 + ((NB) + nj_) * 16 + c) * 32 + xc]; } while (0)
#define MFMA16(AF, BF, NB) do {                                                 \
    _Pragma("unroll") for (int mi_ = 0; mi_ < 8; ++mi_)                         \
      _Pragma("unroll") for (int nj_ = 0; nj_ < 2; ++nj_)                       \
        acc[mi_][(NB) + nj_] = __builtin_amdgcn_mfma_f32_16x16x32_bf16(         \
            AF[mi_], BF[nj_], acc[mi_][(NB) + nj_], 0, 0, 0); } while (0)

#define PH_BAR  asm volatile("s_barrier" ::: "memory")
#define PH_LGKM asm volatile("s_waitcnt lgkmcnt(0)" ::: "memory")

  f32x4 acc[8][4] = {};
  bf16x8 a[8], b[2];

  // prologue: stage tile 0 in cert order; land A_k0,B_k0 (4 stay in flight)
  STAGE_SUB(0, 0); STAGE_SUB(0, 2); STAGE_SUB(0, 1); STAGE_SUB(0, 3);
  asm volatile("s_waitcnt vmcnt(4)" ::: "memory");
  PH_BAR;

  for (int kt = 0; kt < NT64; ++kt) {
    int slot = kt & 1;
    bool st = (kt + 1 < NT64);
    // ---- phase 1: kk0, ni 0-1; stage T+1 A_k0 ----
    READ_A(a, slot, 0);
    READ_B2(b, slot, 0, 0);
    if (st) STAGE_SUB(kt + 1, 0);
    PH_BAR; PH_LGKM;
    __builtin_amdgcn_sched_barrier(0);
    __builtin_amdgcn_s_setprio(1);
    MFMA16(a, b, 0);
    __builtin_amdgcn_s_setprio(0);
    PH_BAR;
    // ---- phase 2: kk0, ni 2-3; stage T+1 B_k0; certify this tile's A_k1,B_k1 ----
    READ_B2(b, slot, 0, 2);
    if (st) { STAGE_SUB(kt + 1, 2);
              asm volatile("s_waitcnt vmcnt(4)" ::: "memory"); }
    else    { asm volatile("s_waitcnt vmcnt(0)" ::: "memory"); }
    PH_BAR; PH_LGKM;
    __builtin_amdgcn_sched_barrier(0);
    __builtin_amdgcn_s_setprio(1);
    MFMA16(a, b, 2);
    __builtin_amdgcn_s_setprio(0);
    PH_BAR;
    // ---- phase 3: kk1, ni 0-1; stage T+1 A_k1 ----
    READ_A(a, slot, 1);
    READ_B2(b, slot, 1, 0);
    if (st) STAGE_SUB(kt + 1, 1);
    PH_BAR; PH_LGKM;
    __builtin_amdgcn_sched_barrier(0);
    __builtin_amdgcn_s_setprio(1);
    MFMA16(a, b, 0);
    __builtin_amdgcn_s_setprio(0);
    PH_BAR;
    // ---- phase 4: kk1, ni 2-3; stage T+1 B_k1; certify T+1's A_k0,B_k0 ----
    READ_B2(b, slot, 1, 2);
    if (st) { STAGE_SUB(kt + 1, 3);
              asm volatile("s_waitcnt vmcnt(4)" ::: "memory"); }
    PH_BAR; PH_LGKM;
    __builtin_amdgcn_sched_barrier(0);
    __builtin_amdgcn_s_setprio(1);
    MFMA16(a, b, 2);
    __builtin_amdgcn_s_setprio(0);
    PH_BAR;
  }
#undef STAGE_SUB
#undef READ_A
#undef READ_B2
#undef MFMA16
#undef PH_BAR
#undef PH_LGKM

  // --- epilogue: dist + fused hard-pos/neg partial select (R6-verified layout) ---
  float pc_[4]; int l2v[4]; int jcol[4];
#pragma unroll
  for (int ni = 0; ni < 4; ++ni) {
    int j = colB + wc * 64 + ni * 16 + c;
    jcol[ni] = j;
    l2v[ni] = lab2[j];
    pc_[ni] = sq2[j] - 2.0f * EPSV * s2[j];
  }
  const float cst = (float)DIM * EPSV * EPSV;
  int partCol = bx * 4 + wc;

#pragma unroll
  for (int mi = 0; mi < 8; ++mi) {
    float posV[4], negV[4]; int posI[4], negI[4];
    float pr[4]; int l1v[4];
#pragma unroll
    for (int r = 0; r < 4; ++r) {
      int i = rowB + wr * 128 + mi * 16 + g * 4 + r;
      l1v[r] = lab1[i];
      pr[r] = sq1[i] + 2.0f * EPSV * s1[i] + cst;
      posV[r] = -3.0e38f; posI[r] = 0x7fffffff;
      negV[r] =  3.0e38f; negI[r] = 0x7fffffff;
    }
#pragma unroll
    for (int ni = 0; ni < 4; ++ni) {
#pragma unroll
      for (int r = 0; r < 4; ++r) {
        float dot = acc[mi][ni][r];
        float d2 = pr[r] + pc_[ni] - 2.0f * dot;
        float dist = sqrtf(fmaxf(d2, 0.0f));
        bool same = (l1v[r] == l2v[ni]);
        float pv = same ? dist : -3.0e38f;
        float nv = same ?  3.0e38f : dist;
        if (pv > posV[r] || (pv == posV[r] && jcol[ni] < posI[r])) { posV[r] = pv; posI[r] = jcol[ni]; }
        if (nv < negV[r] || (nv == negV[r] && jcol[ni] < negI[r])) { negV[r] = nv; negI[r] = jcol[ni]; }
      }
    }
#pragma unroll
    for (int m = 1; m < 16; m <<= 1) {
#pragma unroll
      for (int r = 0; r < 4; ++r) {
        float ov = __shfl_xor(posV[r], m, 64);
        int   oi = __shfl_xor(posI[r], m, 64);
        if (ov > posV[r] || (ov == posV[r] && oi < posI[r])) { posV[r] = ov; posI[r] = oi; }
        float nv2 = __shfl_xor(negV[r], m, 64);
        int   on  = __shfl_xor(negI[r], m, 64);
        if (nv2 < negV[r] || (nv2 == negV[r] && on < negI[r])) { negV[r] = nv2; negI[r] = on; }
      }
    }
    if (c == 0) {
#pragma unroll
      for (int r = 0; r < 4; ++r) {
        int i = rowB + wr * 128 + mi * 16 + g * 4 + r;
        float4 o;
        o.x = posV[r]; o.y = __int_as_float(posI[r]);
        o.z = negV[r]; o.w = __int_as_float(negI[r]);
        part[(size_t)i * 64 + partCol] = o;
      }
    }
  }
}

// ---------------- combine 64 partials per row -> per-row loss directly ----------------
__global__ __launch_bounds__(256) void reduce_kernel(const float4* __restrict__ part,
                                                     float* __restrict__ perrow,
                                                     float* __restrict__ validf) {
  int row = blockIdx.x * 4 + (threadIdx.x >> 6);
  int lane = threadIdx.x & 63;
  float4 p = part[(size_t)row * 64 + lane];
  float posV = p.x; int posI = __float_as_int(p.y);
  float negV = p.z; int negI = __float_as_int(p.w);
#pragma unroll
  for (int m = 1; m < 64; m <<= 1) {
    float ov = __shfl_xor(posV, m, 64);
    int   oi = __shfl_xor(posI, m, 64);
    if (ov > posV || (ov == posV && oi < posI)) { posV = ov; posI = oi; }
    float nv = __shfl_xor(negV, m, 64);
    int   on = __shfl_xor(negI, m, 64);
    if (nv < negV || (nv == negV && on < negI)) { negV = nv; negI = on; }
  }
  if (lane == 0) {
    bool valid = (posV > -1.0e38f && negV < 1.0e38f);
    perrow[row] = valid ? fmaxf(posV - negV, 0.0f) : 0.0f;
    validf[row] = valid ? 1.0f : 0.0f;
  }
}

// ---------------- deterministic finalize (fixed-order tree) ----------------
__global__ __launch_bounds__(256) void finalize_kernel(const float* __restrict__ perrow,
                                                       const float* __restrict__ validf,
                                                       float* __restrict__ out) {
  int t = threadIdx.x;
  float s = 0.f, cv = 0.f;
  for (int i = t; i < BS; i += 256) { s += perrow[i]; cv += validf[i]; }
  __shared__ float ls[256], lc[256];
  ls[t] = s; lc[t] = cv;
  __syncthreads();
  for (int m = 128; m; m >>= 1) {
    if (t < m) { ls[t] += ls[t + m]; lc[t] += lc[t + m]; }
    __syncthreads();
  }
  if (t == 0) out[0] = (lc[0] > 0.f) ? ls[0] / fmaxf(lc[0], 1.f) : 0.f;
}

extern "C" void kernel_launch(void* const* d_in, const int* in_sizes, int n_in,
                              void* d_out, int out_size, void* d_ws, size_t ws_size,
                              hipStream_t stream) {
  const float* h1 = (const float*)d_in[0];
  const float* h2 = (const float*)d_in[1];
  const int* lab1 = (const int*)d_in[2];
  const int* lab2 = (const int*)d_in[3];

  char* ws = (char*)d_ws;
  u16* A = (u16*)ws;
  u16* B = (u16*)(ws + (size_t)BS * DIM * 2);
  size_t off = (size_t)BS * DIM * 4;
  float* sq1 = (float*)(ws + off); off += BS * 4;
  float* s1  = (float*)(ws + off); off += BS * 4;
  float* sq2 = (float*)(ws + off); off += BS * 4;
  float* s2  = (float*)(ws + off); off += BS * 4;
  float4* part = (float4*)(ws + off); off += (size_t)BS * 64 * 16;
  float* perrow = (float*)(ws + off); off += BS * 4;
  float* validf = (float*)(ws + off); off += BS * 4;

  prep_kernel<<<2 * BS, 256, 0, stream>>>(h1, h2, A, B, sq1, s1, sq2, s2);
  gemm_select_kernel<<<256, 512, 0, stream>>>(A, B, sq1, s1, sq2, s2, lab1, lab2, part);
  reduce_kernel<<<BS / 4, 256, 0, stream>>>(part, perrow, validf);
  finalize_kernel<<<1, 256, 0, stream>>>(perrow, validf, (float*)d_out);
}

// Round 14
// 122.054 us; speedup vs baseline: 1.0266x; 1.0266x over previous
//
#include <hip/hip_runtime.h>
#include <hip/hip_bf16.h>
#include <math.h>

#define BS 4096
#define DIM 2048
#define EPSV 1e-6f

typedef unsigned short u16;
typedef float f32x4 __attribute__((ext_vector_type(4)));
typedef __bf16 bf16x8 __attribute__((ext_vector_type(8)));

__device__ inline u16 f2bf(float f) {
  unsigned u = __float_as_uint(f);
  unsigned r = (u + 0x7fffu + ((u >> 16) & 1u)) >> 16;
  return (u16)r;
}

__device__ inline void gload16(const u16* g, u16* l) {
  __builtin_amdgcn_global_load_lds((const __attribute__((address_space(1))) unsigned int*)g,
                                   (__attribute__((address_space(3))) unsigned int*)l,
                                   16, 0, 0);
}

// ---------------- prep: f32 -> bf16 copies + per-row sum / sumsq ----------------
__global__ __launch_bounds__(256) void prep_kernel(
    const float* __restrict__ h1, const float* __restrict__ h2,
    u16* __restrict__ A, u16* __restrict__ B,
    float* __restrict__ sq1, float* __restrict__ s1,
    float* __restrict__ sq2, float* __restrict__ s2) {
  int b = blockIdx.x;
  const float* src; u16* dst; float* sqo; float* so; int row;
  if (b < BS) { src = h1; dst = A; sqo = sq1; so = s1; row = b; }
  else        { src = h2; dst = B; sqo = sq2; so = s2; row = b - BS; }
  src += (size_t)row * DIM;
  dst += (size_t)row * DIM;
  int t = threadIdx.x;
  float sq = 0.f, s = 0.f;
#pragma unroll
  for (int it = 0; it < DIM / (256 * 4); ++it) {
    int idx = (it * 256 + t) * 4;
    float4 v = *(const float4*)(src + idx);
    sq += v.x * v.x + v.y * v.y + v.z * v.z + v.w * v.w;
    s  += v.x + v.y + v.z + v.w;
    ushort4 o;
    o.x = f2bf(v.x); o.y = f2bf(v.y); o.z = f2bf(v.z); o.w = f2bf(v.w);
    *(ushort4*)(dst + idx) = o;
  }
#pragma unroll
  for (int m = 32; m; m >>= 1) { sq += __shfl_xor(sq, m, 64); s += __shfl_xor(s, m, 64); }
  __shared__ float lsq[4], ls[4];
  if ((t & 63) == 0) { lsq[t >> 6] = sq; ls[t >> 6] = s; }
  __syncthreads();
  if (t == 0) {
    sqo[row] = lsq[0] + lsq[1] + lsq[2] + lsq[3];
    so[row]  = ls[0] + ls[1] + ls[2] + ls[3];
  }
}

// ---------------- GEMM: 256x256, BK=32, 4-buffer LDS, X/Y wave-role stagger ----------------
// 512 thr = 8 waves (2M x 4N); group X = wr==0 (waves 0-3), Y = wr==1 (waves 4-7):
// round-robin wave->SIMD puts one X and one Y on each SIMD.
// Per tile T: even phase {stage(T+2); vmcnt(4); X: ds_read frags(T) | Y: MFMA(T-1)};
// barrier; odd phase {X: MFMA(T) | Y: ds_read frags(T)}; barrier.
// MFMA pipe fed every phase (Y then X); the other wave's reads hide beneath.
// 4 buffers (128 KB): buf (T+2)&3 overwritten 4 phases after tile T-2's last
// certified read (compiler lgkm at MFMA use + 2 barriers) -- safe, incl. the
// gload-vs-own-ds_read non-order hazard (stage and read target different bufs).
// Counted vmcnt(4): stage(T+1),(T+2) in flight; tile T certified last iter.
// Swizzle + staging formulas verified in R13 (absmax 0, conflicts 0).
#define BK 32
#define NT (DIM / BK)

__global__ __launch_bounds__(512, 2) void gemm_select_kernel(
    const u16* __restrict__ A, const u16* __restrict__ B,
    const float* __restrict__ sq1, const float* __restrict__ s1,
    const float* __restrict__ sq2, const float* __restrict__ s2,
    const int* __restrict__ lab1, const int* __restrict__ lab2,
    float4* __restrict__ part) {
  __shared__ __align__(16) u16 lds[4][2][8192];  // [buf][A|B][256x32 u16]
  int tid = threadIdx.x;
  int w = tid >> 6, l = tid & 63;
  int wr = w >> 2, wc = w & 3;
  int g = l >> 4, c = l & 15;
  int by = blockIdx.x >> 4, bx = blockIdx.x & 15;
  const int rowB = by * 256, colB = bx * 256;
  const bool isX = (wr == 0);

  // staging (R13-verified): per 16KB sub-array, unit u = q*512+tid,
  // row = q*128 + (tid>>2), logical chunk = (tid&3)^((tid>>3)&3)
  int srow = tid >> 2;
  int schunk = (tid & 3) ^ ((tid >> 3) & 3);
  const u16* gA = A + (size_t)(rowB + srow) * DIM + schunk * 8;
  const u16* gB = B + (size_t)(colB + srow) * DIM + schunk * 8;
  const size_t rstep = (size_t)128 * DIM;

#define STAGE(T) do { int b_ = (T) & 3; size_t k_ = (size_t)(T) * BK;  \
    gload16(gA + k_,         &lds[b_][0][tid * 8]);                     \
    gload16(gA + k_ + rstep, &lds[b_][0][tid * 8 + 4096]);              \
    gload16(gB + k_,         &lds[b_][1][tid * 8]);                     \
    gload16(gB + k_ + rstep, &lds[b_][1][tid * 8 + 4096]); } while (0)

  const int xc = (g ^ ((c >> 1) & 3)) * 8;

#define READF(BUF) do {                                                           \
    _Pragma("unroll") for (int mi_ = 0; mi_ < 8; ++mi_)                           \
      af[mi_] = *(const bf16x8*)&lds[BUF][0][(wr * 128 + mi_ * 16 + c) * 32 + xc];\
    _Pragma("unroll") for (int ni_ = 0; ni_ < 4; ++ni_)                           \
      bf_[ni_] = *(const bf16x8*)&lds[BUF][1][(wc * 64 + ni_ * 16 + c) * 32 + xc]; } while (0)

#define MFMA32 do {                                                               \
    _Pragma("unroll") for (int mi_ = 0; mi_ < 8; ++mi_)                           \
      _Pragma("unroll") for (int ni_ = 0; ni_ < 4; ++ni_)                         \
        acc[mi_][ni_] = __builtin_amdgcn_mfma_f32_16x16x32_bf16(                  \
            af[mi_], bf_[ni_], acc[mi_][ni_], 0, 0, 0); } while (0)

  f32x4 acc[8][4] = {};
  bf16x8 af[8], bf_[4];

  // prologue: stage tiles 0,1; certify tile 0 (tile 1 stays in flight)
  STAGE(0); STAGE(1);
  asm volatile("s_waitcnt vmcnt(4)" ::: "memory");
  asm volatile("s_barrier" ::: "memory");

  for (int T = 0; T < NT; ++T) {
    int b = T & 3;
    // even phase: stage + certify; X reads tile T, Y computes tile T-1
    if (T + 2 < NT) { STAGE(T + 2); asm volatile("s_waitcnt vmcnt(4)" ::: "memory"); }
    else            { asm volatile("s_waitcnt vmcnt(0)" ::: "memory"); }
    if (isX)        { READF(b); }
    else if (T > 0) { MFMA32; }
    asm volatile("s_barrier" ::: "memory");
    // odd phase: X computes tile T, Y reads tile T
    if (isX) { MFMA32; }
    else     { READF(b); }
    asm volatile("s_barrier" ::: "memory");
  }
  if (!isX) { MFMA32; }  // Y finishes tile NT-1
#undef STAGE
#undef READF
#undef MFMA32

  // --- epilogue: dist + fused hard-pos/neg partial select (R13-verified layout) ---
  float pc_[4]; int l2v[4]; int jcol[4];
#pragma unroll
  for (int ni = 0; ni < 4; ++ni) {
    int j = colB + wc * 64 + ni * 16 + c;
    jcol[ni] = j;
    l2v[ni] = lab2[j];
    pc_[ni] = sq2[j] - 2.0f * EPSV * s2[j];
  }
  const float cst = (float)DIM * EPSV * EPSV;
  int partCol = bx * 4 + wc;

#pragma unroll
  for (int mi = 0; mi < 8; ++mi) {
    float posV[4], negV[4]; int posI[4], negI[4];
    float pr[4]; int l1v[4];
#pragma unroll
    for (int r = 0; r < 4; ++r) {
      int i = rowB + wr * 128 + mi * 16 + g * 4 + r;
      l1v[r] = lab1[i];
      pr[r] = sq1[i] + 2.0f * EPSV * s1[i] + cst;
      posV[r] = -3.0e38f; posI[r] = 0x7fffffff;
      negV[r] =  3.0e38f; negI[r] = 0x7fffffff;
    }
#pragma unroll
    for (int ni = 0; ni < 4; ++ni) {
#pragma unroll
      for (int r = 0; r < 4; ++r) {
        float dot = acc[mi][ni][r];
        float d2 = pr[r] + pc_[ni] - 2.0f * dot;
        float dist = sqrtf(fmaxf(d2, 0.0f));
        bool same = (l1v[r] == l2v[ni]);
        float pv = same ? dist : -3.0e38f;
        float nv = same ?  3.0e38f : dist;
        if (pv > posV[r] || (pv == posV[r] && jcol[ni] < posI[r])) { posV[r] = pv; posI[r] = jcol[ni]; }
        if (nv < negV[r] || (nv == negV[r] && jcol[ni] < negI[r])) { negV[r] = nv; negI[r] = jcol[ni]; }
      }
    }
#pragma unroll
    for (int m = 1; m < 16; m <<= 1) {
#pragma unroll
      for (int r = 0; r < 4; ++r) {
        float ov = __shfl_xor(posV[r], m, 64);
        int   oi = __shfl_xor(posI[r], m, 64);
        if (ov > posV[r] || (ov == posV[r] && oi < posI[r])) { posV[r] = ov; posI[r] = oi; }
        float nv2 = __shfl_xor(negV[r], m, 64);
        int   on  = __shfl_xor(negI[r], m, 64);
        if (nv2 < negV[r] || (nv2 == negV[r] && on < negI[r])) { negV[r] = nv2; negI[r] = on; }
      }
    }
    if (c == 0) {
#pragma unroll
      for (int r = 0; r < 4; ++r) {
        int i = rowB + wr * 128 + mi * 16 + g * 4 + r;
        float4 o;
        o.x = posV[r]; o.y = __int_as_float(posI[r]);
        o.z = negV[r]; o.w = __int_as_float(negI[r]);
        part[(size_t)i * 64 + partCol] = o;
      }
    }
  }
}

// ---------------- combine 64 partials per row -> per-row loss directly ----------------
__global__ __launch_bounds__(256) void reduce_kernel(const float4* __restrict__ part,
                                                     float* __restrict__ perrow,
                                                     float* __restrict__ validf) {
  int row = blockIdx.x * 4 + (threadIdx.x >> 6);
  int lane = threadIdx.x & 63;
  float4 p = part[(size_t)row * 64 + lane];
  float posV = p.x; int posI = __float_as_int(p.y);
  float negV = p.z; int negI = __float_as_int(p.w);
#pragma unroll
  for (int m = 1; m < 64; m <<= 1) {
    float ov = __shfl_xor(posV, m, 64);
    int   oi = __shfl_xor(posI, m, 64);
    if (ov > posV || (ov == posV && oi < posI)) { posV = ov; posI = oi; }
    float nv = __shfl_xor(negV, m, 64);
    int   on = __shfl_xor(negI, m, 64);
    if (nv < negV || (nv == negV && on < negI)) { negV = nv; negI = on; }
  }
  if (lane == 0) {
    bool valid = (posV > -1.0e38f && negV < 1.0e38f);
    perrow[row] = valid ? fmaxf(posV - negV, 0.0f) : 0.0f;
    validf[row] = valid ? 1.0f : 0.0f;
  }
}

// ---------------- deterministic finalize (fixed-order tree) ----------------
__global__ __launch_bounds__(256) void finalize_kernel(const float* __restrict__ perrow,
                                                       const float* __restrict__ validf,
                                                       float* __restrict__ out) {
  int t = threadIdx.x;
  float s = 0.f, cv = 0.f;
  for (int i = t; i < BS; i += 256) { s += perrow[i]; cv += validf[i]; }
  __shared__ float ls[256], lc[256];
  ls[t] = s; lc[t] = cv;
  __syncthreads();
  for (int m = 128; m; m >>= 1) {
    if (t < m) { ls[t] += ls[t + m]; lc[t] += lc[t + m]; }
    __syncthreads();
  }
  if (t == 0) out[0] = (lc[0] > 0.f) ? ls[0] / fmaxf(lc[0], 1.f) : 0.f;
}

extern "C" void kernel_launch(void* const* d_in, const int* in_sizes, int n_in,
                              void* d_out, int out_size, void* d_ws, size_t ws_size,
                              hipStream_t stream) {
  const float* h1 = (const float*)d_in[0];
  const float* h2 = (const float*)d_in[1];
  const int* lab1 = (const int*)d_in[2];
  const int* lab2 = (const int*)d_in[3];

  char* ws = (char*)d_ws;
  u16* A = (u16*)ws;
  u16* B = (u16*)(ws + (size_t)BS * DIM * 2);
  size_t off = (size_t)BS * DIM * 4;
  float* sq1 = (float*)(ws + off); off += BS * 4;
  float* s1  = (float*)(ws + off); off += BS * 4;
  float* sq2 = (float*)(ws + off); off += BS * 4;
  float* s2  = (float*)(ws + off); off += BS * 4;
  float4* part = (float4*)(ws + off); off += (size_t)BS * 64 * 16;
  float* perrow = (float*)(ws + off); off += BS * 4;
  float* validf = (float*)(ws + off); off += BS * 4;

  prep_kernel<<<2 * BS, 256, 0, stream>>>(h1, h2, A, B, sq1, s1, sq2, s2);
  gemm_select_kernel<<<256, 512, 0, stream>>>(A, B, sq1, s1, sq2, s2, lab1, lab2, part);
  reduce_kernel<<<BS / 4, 256, 0, stream>>>(part, perrow, validf);
  finalize_kernel<<<1, 256, 0, stream>>>(perrow, validf, (float*)d_out);
}

// Round 17
// 114.624 us; speedup vs baseline: 1.0931x; 1.0648x over previous
//
#include <hip/hip_runtime.h>
#include <hip/hip_bf16.h>
#include <math.h>

#define BS 4096
#define DIM 2048
#define EPSV 1e-6f

typedef unsigned char u8;
typedef unsigned long long u64;
typedef long i64;
typedef float f32x4 __attribute__((ext_vector_type(4)));

// f32 -> e4m3fn (OCP), RNE, FTZ below 2^-6, clamp to 448. For N(0,1) data the
// FTZ/clamp paths are negligible (P(|x|<2^-6)~1.2%, contribution << fp8 noise).
__device__ inline u8 f2e4m3(float f) {
  unsigned u = __float_as_uint(f);
  unsigned s = (u >> 24) & 0x80u;
  unsigned ae = u & 0x7FFFFFFFu;
  if (ae < 0x3C800000u) return (u8)s;        // |x| < 2^-6 -> signed zero
  if (ae > 0x43E00000u) ae = 0x43E00000u;    // clamp to 448
  unsigned r = ae + 0x7FFFFu + ((ae >> 20) & 1u);  // RNE on 20 dropped bits
  unsigned e = (r >> 23) & 0xFFu;                  // 121..135
  return (u8)(s | ((e - 120u) << 3) | ((r >> 20) & 7u));
}

__device__ inline void gload16(const u8* g, u8* l) {
  __builtin_amdgcn_global_load_lds((const __attribute__((address_space(1))) unsigned int*)g,
                                   (__attribute__((address_space(3))) unsigned int*)l,
                                   16, 0, 0);
}

// ---------------- prep: f32 -> fp8 e4m3 copies + per-row sum / sumsq (f32-exact) ----------------
__global__ __launch_bounds__(256) void prep_kernel(
    const float* __restrict__ h1, const float* __restrict__ h2,
    u8* __restrict__ A, u8* __restrict__ B,
    float* __restrict__ sq1, float* __restrict__ s1,
    float* __restrict__ sq2, float* __restrict__ s2) {
  int b = blockIdx.x;
  const float* src; u8* dst; float* sqo; float* so; int row;
  if (b < BS) { src = h1; dst = A; sqo = sq1; so = s1; row = b; }
  else        { src = h2; dst = B; sqo = sq2; so = s2; row = b - BS; }
  src += (size_t)row * DIM;
  dst += (size_t)row * DIM;
  int t = threadIdx.x;
  // 256 threads x 8 elems = 2048 = DIM (single pass)
  int idx = t * 8;
  float4 v0 = *(const float4*)(src + idx);
  float4 v1 = *(const float4*)(src + idx + 4);
  float sq = v0.x*v0.x + v0.y*v0.y + v0.z*v0.z + v0.w*v0.w
           + v1.x*v1.x + v1.y*v1.y + v1.z*v1.z + v1.w*v1.w;
  float s  = v0.x + v0.y + v0.z + v0.w + v1.x + v1.y + v1.z + v1.w;
  u64 pk = (u64)f2e4m3(v0.x)
         | ((u64)f2e4m3(v0.y) << 8)
         | ((u64)f2e4m3(v0.z) << 16)
         | ((u64)f2e4m3(v0.w) << 24)
         | ((u64)f2e4m3(v1.x) << 32)
         | ((u64)f2e4m3(v1.y) << 40)
         | ((u64)f2e4m3(v1.z) << 48)
         | ((u64)f2e4m3(v1.w) << 56);
  *(u64*)(dst + idx) = pk;
#pragma unroll
  for (int m = 32; m; m >>= 1) { sq += __shfl_xor(sq, m, 64); s += __shfl_xor(s, m, 64); }
  __shared__ float lsq[4], ls[4];
  if ((t & 63) == 0) { lsq[t >> 6] = sq; ls[t >> 6] = s; }
  __syncthreads();
  if (t == 0) {
    sqo[row] = lsq[0] + lsq[1] + lsq[2] + lsq[3];
    so[row]  = ls[0] + ls[1] + ls[2] + ls[3];
  }
}

// ---------------- GEMM (fp8 e4m3, R10 geometry): 256x128 tile, BK=32, dbuf, 2 blocks/CU ----------
// 512 thr = 8 waves (4M x 2N), wave tile 64x64, acc[4][4]=64 regs.
// fp8 halves all LDS/staging bytes vs bf16 -> MFMA becomes the floor.
// LDS per buffer: A 256x32B (8 KB) + B 128x32B (4 KB) = 12 KB; dbuf 24 KB.
// Swizzle (32B rows): slot8 = g ^ ((row>>2)&1)*2 -> 2-way bank conflicts (free).
// Staging involution: 16B unit u=tid -> row=u>>1, k-offset ((u&1)^((u>>3)&1))*16
// (contiguous 16B since swz is even). Frag = 8 B (i64) per mfma_16x16x32_fp8.
#define BK 32
#define NT (DIM / BK)

__global__ __launch_bounds__(512, 4) void gemm_select_kernel(
    const u8* __restrict__ A, const u8* __restrict__ B,
    const float* __restrict__ sq1, const float* __restrict__ s1,
    const float* __restrict__ sq2, const float* __restrict__ s2,
    const int* __restrict__ lab1, const int* __restrict__ lab2,
    float4* __restrict__ part) {
  __shared__ __align__(16) u8 lds[2][12288];  // [buf][A 8192 | B 4096]
  int tid = threadIdx.x;
  int w = tid >> 6, l = tid & 63;
  int wr = w >> 1, wc = w & 1;
  int g = l >> 4, c = l & 15;
  int by = blockIdx.x >> 5, bx = blockIdx.x & 31;
  const int rowB = by * 256, colB = bx * 128;

  // staging: pre-swizzled global source, linear LDS dest (rule #21)
  int srow = tid >> 1;
  int koff = (((tid & 1) ^ ((tid >> 3) & 1)) * 16);
  const u8* gA = A + (size_t)(rowB + srow) * DIM + koff;             // all 512 thr
  const u8* gB = B + (size_t)(colB + (srow & 127)) * DIM + koff;     // tid<256 only

#define STAGE(T) do { int b_ = (T) & 1; size_t k_ = (size_t)(T) * BK;  \
    gload16(gA + k_, &lds[b_][tid * 16]);                               \
    if (tid < 256) gload16(gB + k_, &lds[b_][8192 + tid * 16]); } while (0)

  // fragment reads: slot8 = g ^ ((c>>2)&1)*2 (row-bit2 == c-bit2 for all frags)
  const int slot = (g ^ (((c >> 2) & 1) * 2)) * 8;

  f32x4 acc[4][4] = {};

  STAGE(0);
  __syncthreads();

  for (int kt = 0; kt < NT; ++kt) {
    const u8* buf = lds[kt & 1];
    if (kt + 1 < NT) STAGE(kt + 1);
    i64 af[4], bfr[4];
#pragma unroll
    for (int mi = 0; mi < 4; ++mi)
      af[mi] = *(const i64*)&buf[(wr * 64 + mi * 16 + c) * 32 + slot];
#pragma unroll
    for (int ni = 0; ni < 4; ++ni)
      bfr[ni] = *(const i64*)&buf[8192 + (wc * 64 + ni * 16 + c) * 32 + slot];
#pragma unroll
    for (int mi = 0; mi < 4; ++mi)
#pragma unroll
      for (int ni = 0; ni < 4; ++ni)
        acc[mi][ni] = __builtin_amdgcn_mfma_f32_16x16x32_fp8_fp8(af[mi], bfr[ni], acc[mi][ni], 0, 0, 0);
    __syncthreads();
  }
#undef STAGE

  // --- epilogue: dist + fused hard-pos/neg partial select (fp8 dist, select only) ---
  float pc_[4]; int l2v[4]; int jcol[4];
#pragma unroll
  for (int ni = 0; ni < 4; ++ni) {
    int j = colB + wc * 64 + ni * 16 + c;
    jcol[ni] = j;
    l2v[ni] = lab2[j];
    pc_[ni] = sq2[j] - 2.0f * EPSV * s2[j];
  }
  const float cst = (float)DIM * EPSV * EPSV;
  int partCol = bx * 2 + wc;

#pragma unroll
  for (int mi = 0; mi < 4; ++mi) {
    float posV[4], negV[4]; int posI[4], negI[4];
    float pr[4]; int l1v[4];
#pragma unroll
    for (int r = 0; r < 4; ++r) {
      int i = rowB + wr * 64 + mi * 16 + g * 4 + r;
      l1v[r] = lab1[i];
      pr[r] = sq1[i] + 2.0f * EPSV * s1[i] + cst;
      posV[r] = -3.0e38f; posI[r] = 0x7fffffff;
      negV[r] =  3.0e38f; negI[r] = 0x7fffffff;
    }
#pragma unroll
    for (int ni = 0; ni < 4; ++ni) {
#pragma unroll
      for (int r = 0; r < 4; ++r) {
        float dot = acc[mi][ni][r];
        float d2 = pr[r] + pc_[ni] - 2.0f * dot;
        float dist = sqrtf(fmaxf(d2, 0.0f));
        bool same = (l1v[r] == l2v[ni]);
        float pv = same ? dist : -3.0e38f;
        float nv = same ?  3.0e38f : dist;
        if (pv > posV[r] || (pv == posV[r] && jcol[ni] < posI[r])) { posV[r] = pv; posI[r] = jcol[ni]; }
        if (nv < negV[r] || (nv == negV[r] && jcol[ni] < negI[r])) { negV[r] = nv; negI[r] = jcol[ni]; }
      }
    }
#pragma unroll
    for (int m = 1; m < 16; m <<= 1) {
#pragma unroll
      for (int r = 0; r < 4; ++r) {
        float ov = __shfl_xor(posV[r], m, 64);
        int   oi = __shfl_xor(posI[r], m, 64);
        if (ov > posV[r] || (ov == posV[r] && oi < posI[r])) { posV[r] = ov; posI[r] = oi; }
        float nv2 = __shfl_xor(negV[r], m, 64);
        int   on  = __shfl_xor(negI[r], m, 64);
        if (nv2 < negV[r] || (nv2 == negV[r] && on < negI[r])) { negV[r] = nv2; negI[r] = on; }
      }
    }
    if (c == 0) {
#pragma unroll
      for (int r = 0; r < 4; ++r) {
        int i = rowB + wr * 64 + mi * 16 + g * 4 + r;
        float4 o;
        o.x = posV[r]; o.y = __int_as_float(posI[r]);
        o.z = negV[r]; o.w = __int_as_float(negI[r]);
        part[(size_t)i * 64 + partCol] = o;
      }
    }
  }
}

// ---------------- combine 64 partials per row -> selected indices ----------------
__global__ __launch_bounds__(256) void reduce_kernel(const float4* __restrict__ part,
                                                     int4* __restrict__ sel) {
  int row = blockIdx.x * 4 + (threadIdx.x >> 6);
  int lane = threadIdx.x & 63;
  float4 p = part[(size_t)row * 64 + lane];
  float posV = p.x; int posI = __float_as_int(p.y);
  float negV = p.z; int negI = __float_as_int(p.w);
#pragma unroll
  for (int m = 1; m < 64; m <<= 1) {
    float ov = __shfl_xor(posV, m, 64);
    int   oi = __shfl_xor(posI, m, 64);
    if (ov > posV || (ov == posV && oi < posI)) { posV = ov; posI = oi; }
    float nv = __shfl_xor(negV, m, 64);
    int   on = __shfl_xor(negI, m, 64);
    if (nv < negV || (nv == negV && on < negI)) { negV = nv; negI = on; }
  }
  if (lane == 0) {
    int valid = (posV > -1.0e38f && negV < 1.0e38f) ? 1 : 0;
    sel[row] = make_int4(posI, negI, valid, 0);
  }
}

// ---------------- recompute d_ap / d_an exactly (f32, direct formula; R4-verified) --------------
__global__ __launch_bounds__(256) void loss_kernel(
    const float* __restrict__ h1, const float* __restrict__ h2,
    const int4* __restrict__ sel, float* __restrict__ perrow, float* __restrict__ validf) {
  int row = blockIdx.x;
  int t = threadIdx.x;
  int4 sl = sel[row];
  if (!sl.z) { if (t == 0) { perrow[row] = 0.f; validf[row] = 0.f; } return; }
  const float* x = h1 + (size_t)row * DIM;
  const float* p = h2 + (size_t)sl.x * DIM;
  const float* n = h2 + (size_t)sl.y * DIM;
  float sap = 0.f, san = 0.f;
#pragma unroll
  for (int it = 0; it < DIM / (256 * 4); ++it) {
    int idx = (it * 256 + t) * 4;
    float4 xv = *(const float4*)(x + idx);
    float4 pv = *(const float4*)(p + idx);
    float4 nv = *(const float4*)(n + idx);
    float d;
    d = xv.x - pv.x + EPSV; sap += d * d;
    d = xv.y - pv.y + EPSV; sap += d * d;
    d = xv.z - pv.z + EPSV; sap += d * d;
    d = xv.w - pv.w + EPSV; sap += d * d;
    d = xv.x - nv.x + EPSV; san += d * d;
    d = xv.y - nv.y + EPSV; san += d * d;
    d = xv.z - nv.z + EPSV; san += d * d;
    d = xv.w - nv.w + EPSV; san += d * d;
  }
#pragma unroll
  for (int m = 32; m; m >>= 1) { sap += __shfl_xor(sap, m, 64); san += __shfl_xor(san, m, 64); }
  __shared__ float lsap[4], lsan[4];
  if ((t & 63) == 0) { lsap[t >> 6] = sap; lsan[t >> 6] = san; }
  __syncthreads();
  if (t == 0) {
    sap = lsap[0] + lsap[1] + lsap[2] + lsap[3];
    san = lsan[0] + lsan[1] + lsan[2] + lsan[3];
    perrow[row] = fmaxf(sqrtf(sap) - sqrtf(san), 0.0f);
    validf[row] = 1.0f;
  }
}

// ---------------- deterministic finalize (fixed-order tree) ----------------
__global__ __launch_bounds__(256) void finalize_kernel(const float* __restrict__ perrow,
                                                       const float* __restrict__ validf,
                                                       float* __restrict__ out) {
  int t = threadIdx.x;
  float s = 0.f, cv = 0.f;
  for (int i = t; i < BS; i += 256) { s += perrow[i]; cv += validf[i]; }
  __shared__ float ls[256], lc[256];
  ls[t] = s; lc[t] = cv;
  __syncthreads();
  for (int m = 128; m; m >>= 1) {
    if (t < m) { ls[t] += ls[t + m]; lc[t] += lc[t + m]; }
    __syncthreads();
  }
  if (t == 0) out[0] = (lc[0] > 0.f) ? ls[0] / fmaxf(lc[0], 1.f) : 0.f;
}

extern "C" void kernel_launch(void* const* d_in, const int* in_sizes, int n_in,
                              void* d_out, int out_size, void* d_ws, size_t ws_size,
                              hipStream_t stream) {
  const float* h1 = (const float*)d_in[0];
  const float* h2 = (const float*)d_in[1];
  const int* lab1 = (const int*)d_in[2];
  const int* lab2 = (const int*)d_in[3];

  char* ws = (char*)d_ws;
  u8* A = (u8*)ws;
  u8* B = (u8*)(ws + (size_t)BS * DIM);
  size_t off = (size_t)BS * DIM * 2;
  float* sq1 = (float*)(ws + off); off += BS * 4;
  float* s1  = (float*)(ws + off); off += BS * 4;
  float* sq2 = (float*)(ws + off); off += BS * 4;
  float* s2  = (float*)(ws + off); off += BS * 4;
  float4* part = (float4*)(ws + off); off += (size_t)BS * 64 * 16;
  int4* sel = (int4*)(ws + off); off += BS * 16;
  float* perrow = (float*)(ws + off); off += BS * 4;
  float* validf = (float*)(ws + off); off += BS * 4;

  prep_kernel<<<2 * BS, 256, 0, stream>>>(h1, h2, A, B, sq1, s1, sq2, s2);
  gemm_select_kernel<<<512, 512, 0, stream>>>(A, B, sq1, s1, sq2, s2, lab1, lab2, part);
  reduce_kernel<<<BS / 4, 256, 0, stream>>>(part, sel);
  loss_kernel<<<BS, 256, 0, stream>>>(h1, h2, sel, perrow, validf);
  finalize_kernel<<<1, 256, 0, stream>>>(perrow, validf, (float*)d_out);
}